// Round 1
// baseline (1799.193 us; speedup 1.0000x reference)
//
#include <hip/hip_runtime.h>
#include <cstddef>

// StackLSTM: T=64, B=128, H=256, L=2
#define TT 64
#define BB 128
#define HH 256
#define G4 1024  // 4*H

// ws layout (float offsets)
#define OFF_XG      0u         // [T*B][1024]   = 8,388,608 floats
#define OFF_WTIH0   8388608u   // [256][1024]   W_ih[0]^T
#define OFF_WT0     8650752u   // [256][1024]   W_hh[0]^T
#define OFF_WTI1    8912896u   // [256][1024]   W_ih[1]^T
#define OFF_WTH1    9175040u   // [256][1024]   W_hh[1]^T
#define OFF_HSTACK  9437184u   // [65][B][2][256] = 4,259,840 floats
#define OFF_CSTACK  13697024u  // [65][B][2][256]
// total 17,956,864 floats = 71.8 MB

__device__ __forceinline__ float sigf(float x) { return 1.0f / (1.0f + expf(-x)); }

// ---------------------------------------------------------------------------
// Kernel 1: transpose the 4 weight matrices [1024][256] -> [256][1024]
// grid (32, 8, 4), block (32, 8)
// ---------------------------------------------------------------------------
__global__ void transpose4(const float* __restrict__ W_ih,
                           const float* __restrict__ W_hh,
                           float* __restrict__ ws) {
  const int z = blockIdx.z;
  const float* src = (z == 0) ? W_ih
                   : (z == 1) ? W_hh
                   : (z == 2) ? (W_ih + G4 * HH)
                              : (W_hh + G4 * HH);
  float* dst = (z == 0) ? (ws + OFF_WTIH0)
             : (z == 1) ? (ws + OFF_WT0)
             : (z == 2) ? (ws + OFF_WTI1)
                        : (ws + OFF_WTH1);
  __shared__ float tile[32][33];
  const int g0 = blockIdx.x * 32;   // row block in source (gate dim, 1024)
  const int k0 = blockIdx.y * 32;   // col block in source (k dim, 256)
  const int tx = threadIdx.x;       // 0..31
  const int ty = threadIdx.y;       // 0..7
#pragma unroll
  for (int i = 0; i < 32; i += 8)
    tile[ty + i][tx] = src[(size_t)(g0 + ty + i) * HH + k0 + tx];
  __syncthreads();
#pragma unroll
  for (int i = 0; i < 32; i += 8)
    dst[(size_t)(k0 + ty + i) * G4 + g0 + tx] = tile[tx][ty + i];
}

// ---------------------------------------------------------------------------
// Kernel 2: Xg[t*B+b][g] = b_ih0[g] + sum_k x[t,b,k] * W_ih0[g][k]
// grid (512, 4), block 256. Each WG: 16 rows x 256 gate cols.
// ---------------------------------------------------------------------------
__global__ void xg_kernel(const float* __restrict__ x,
                          const float* __restrict__ b_ih,
                          float* __restrict__ ws) {
  const float* __restrict__ WTih0 = ws + OFF_WTIH0;
  float* __restrict__ Xg = ws + OFF_XG;
  const int r0 = blockIdx.x * 16;
  const int g = blockIdx.y * 256 + threadIdx.x;

  __shared__ float xs[16][HH];
  for (int i = threadIdx.x; i < 16 * HH; i += 256) {
    const int r = i >> 8;       // i / 256
    const int k = i & 255;      // == threadIdx.x each pass -> coalesced
    xs[r][k] = x[(size_t)(r0 + r) * HH + k];
  }
  __syncthreads();

  float acc[16];
  const float bias = b_ih[g];
#pragma unroll
  for (int r = 0; r < 16; ++r) acc[r] = bias;

  for (int k = 0; k < HH; ++k) {
    const float w = WTih0[(size_t)k * G4 + g];
#pragma unroll
    for (int r = 0; r < 16; ++r) acc[r] = fmaf(xs[r][k], w, acc[r]);
  }
#pragma unroll
  for (int r = 0; r < 16; ++r)
    Xg[(size_t)(r0 + r) * G4 + g] = acc[r];
}

// ---------------------------------------------------------------------------
// Kernel 3: the sequential stack-LSTM. One workgroup per batch element.
// grid 128, block 1024. Thread tid computes gate column tid each layer;
// threads 0..255 do the elementwise cell update for h-col tid.
// ---------------------------------------------------------------------------
__global__ void __launch_bounds__(1024)
seq_kernel(const float* __restrict__ b_ih,
           const float* __restrict__ b_hh,
           const int* __restrict__ ops,
           float* __restrict__ ws,
           float* __restrict__ out) {
  const int b = blockIdx.x;
  const int tid = threadIdx.x;

  const float* __restrict__ Xg   = ws + OFF_XG;
  const float* __restrict__ WT0  = ws + OFF_WT0;
  const float* __restrict__ WTI1 = ws + OFF_WTI1;
  const float* __restrict__ WTH1 = ws + OFF_WTH1;
  float* __restrict__ hstack = ws + OFF_HSTACK;
  float* __restrict__ cstack = ws + OFF_CSTACK;

  __shared__ float hprev0[HH];
  __shared__ float hprev1[HH];
  __shared__ float h0s[HH];
  __shared__ float gat[G4];

  // step-invariant biases (b_ih[0] is folded into Xg)
  const float bias0 = b_hh[tid];                       // layer 0: b_hh[0][tid]
  const float bias1 = b_ih[G4 + tid] + b_hh[G4 + tid]; // layer 1

  int pos = 0;
  for (int t = 0; t < TT; ++t) {
    // ---- gather top-of-stack hidden states into LDS ----
    if (tid < HH) {
      float v0 = 0.f, v1 = 0.f;
      if (pos > 0) {
        const size_t base = ((size_t)pos * BB + b) * 2 * HH;
        v0 = hstack[base + tid];
        v1 = hstack[base + HH + tid];
      }
      hprev0[tid] = v0;
      hprev1[tid] = v1;
    }
    __syncthreads();

    // ---- layer 0 gates: Xg + b_hh0 + hprev0 @ W_hh0^T ----
    {
      float acc = bias0 + Xg[((size_t)t * BB + b) * G4 + tid];
      const float* __restrict__ wp = WT0 + tid;
#pragma unroll 8
      for (int k = 0; k < HH; ++k)
        acc = fmaf(hprev0[k], wp[(size_t)k * G4], acc);
      gat[tid] = acc;
    }
    __syncthreads();

    // ---- layer 0 cell update ----
    if (tid < HH) {
      const float ig = gat[tid];
      const float fg = gat[HH + tid];
      const float gg = gat[2 * HH + tid];
      const float og = gat[3 * HH + tid];
      float cp = 0.f;
      if (pos > 0) cp = cstack[((size_t)pos * BB + b) * 2 * HH + tid];
      const float c = sigf(fg) * cp + sigf(ig) * tanhf(gg);
      const float h = sigf(og) * tanhf(c);
      h0s[tid] = h;
      const size_t wbase = ((size_t)(pos + 1) * BB + b) * 2 * HH;
      hstack[wbase + tid] = h;
      cstack[wbase + tid] = c;
    }
    __syncthreads();

    // ---- layer 1 gates: b_ih1 + b_hh1 + h0 @ W_ih1^T + hprev1 @ W_hh1^T ----
    {
      float acc = bias1;
      const float* __restrict__ wi = WTI1 + tid;
      const float* __restrict__ wh = WTH1 + tid;
#pragma unroll 8
      for (int k = 0; k < HH; ++k)
        acc = fmaf(h0s[k], wi[(size_t)k * G4], acc);
#pragma unroll 8
      for (int k = 0; k < HH; ++k)
        acc = fmaf(hprev1[k], wh[(size_t)k * G4], acc);
      gat[tid] = acc;
    }
    __syncthreads();

    // ---- layer 1 cell update + stack write + output ----
    if (tid < HH) {
      const float ig = gat[tid];
      const float fg = gat[HH + tid];
      const float gg = gat[2 * HH + tid];
      const float og = gat[3 * HH + tid];
      float cp = 0.f;
      if (pos > 0) cp = cstack[((size_t)pos * BB + b) * 2 * HH + HH + tid];
      const float c = sigf(fg) * cp + sigf(ig) * tanhf(gg);
      const float h = sigf(og) * tanhf(c);
      const size_t wbase = ((size_t)(pos + 1) * BB + b) * 2 * HH + HH;
      hstack[wbase + tid] = h;
      cstack[wbase + tid] = c;
      out[((size_t)t * BB + b) * HH + tid] = h;
    }

    pos += ops[t * BB + b];
    __syncthreads();  // protect LDS reuse + stack visibility for next step
  }
}

// ---------------------------------------------------------------------------
extern "C" void kernel_launch(void* const* d_in, const int* in_sizes, int n_in,
                              void* d_out, int out_size, void* d_ws, size_t ws_size,
                              hipStream_t stream) {
  const float* x    = (const float*)d_in[0];
  const int*   ops  = (const int*)d_in[1];
  const float* W_ih = (const float*)d_in[2];
  const float* W_hh = (const float*)d_in[3];
  const float* b_ih = (const float*)d_in[4];
  const float* b_hh = (const float*)d_in[5];
  float* out = (float*)d_out;
  float* ws  = (float*)d_ws;

  // 1) transpose weights to K-major for coalesced streaming
  transpose4<<<dim3(32, 8, 4), dim3(32, 8), 0, stream>>>(W_ih, W_hh, ws);

  // 2) precompute Xg = x @ W_ih[0]^T + b_ih[0] for all T*B rows
  xg_kernel<<<dim3(512, 4), 256, 0, stream>>>(x, b_ih, ws);

  // 3) sequential recurrence, one WG per batch element
  seq_kernel<<<BB, 1024, 0, stream>>>(b_ih, b_hh, ops, ws, out);
}

// Round 2
// 1508.103 us; speedup vs baseline: 1.1930x; 1.1930x over previous
//
#include <hip/hip_runtime.h>
#include <cstddef>

// StackLSTM: T=64, B=128, H=256, L=2.  ops∈{0,1} => stack never pops:
// top-of-stack h/c live in LDS/registers; no global stacks at all.
#define TT 64
#define BB 128
#define HH 256
#define G4 1024  // 4*H

// ws layout (float-slot offsets)
#define OFF_XG      0u         // [T*B][1024] fp32 = 8,388,608 floats
#define OFF_WTIH0   8388608u   // [256][1024] fp32 W_ih[0]^T (for xg)
#define OFF_PWHH0   8650752u   // uint32 [128 k2][1024 g]  bf16-pair packed
#define OFF_PWIH1   8781824u
#define OFF_PWHH1   8912896u
#define OFF_HX0     9043968u   // [128 b][256] fp32 h0 exchange
#define OFF_HX1     9076736u   // [128 b][256] fp32 h1 exchange
#define OFF_FLAGS   9109504u   // uint flagsA[2][128], flagsB[2][128]
// total ~9.11M floats = 36.5 MB  (< previous 71.8 MB, fits ws)

__device__ __forceinline__ float sigf(float x) { return 1.0f / (1.0f + expf(-x)); }
__device__ __forceinline__ float blo(unsigned u) { return __uint_as_float(u << 16); }
__device__ __forceinline__ float bhi(unsigned u) { return __uint_as_float(u & 0xffff0000u); }
__device__ __forceinline__ unsigned short f2bf(float x) {  // RNE
  unsigned u = __float_as_uint(x);
  return (unsigned short)((u + 0x7fffu + ((u >> 16) & 1u)) >> 16);
}

// ---------------------------------------------------------------------------
// transpose W_ih[0] [1024][256] -> [256][1024] fp32 (for xg_kernel)
// ---------------------------------------------------------------------------
__global__ void transpose1(const float* __restrict__ W_ih, float* __restrict__ ws) {
  __shared__ float tile[32][33];
  float* dst = ws + OFF_WTIH0;
  const int g0 = blockIdx.x * 32, k0 = blockIdx.y * 32;
  const int tx = threadIdx.x, ty = threadIdx.y;
#pragma unroll
  for (int i = 0; i < 32; i += 8)
    tile[ty + i][tx] = W_ih[(size_t)(g0 + ty + i) * HH + k0 + tx];
  __syncthreads();
#pragma unroll
  for (int i = 0; i < 32; i += 8)
    dst[(size_t)(k0 + ty + i) * G4 + g0 + tx] = tile[tx][ty + i];
}

// ---------------------------------------------------------------------------
// pack W_hh[0], W_ih[1], W_hh[1] into bf16-pair uint32 arrays [k2][1024]
// ---------------------------------------------------------------------------
__global__ void pack_bf16(const float* __restrict__ W_ih,
                          const float* __restrict__ W_hh,
                          float* __restrict__ ws) {
  const int m = blockIdx.y;
  const float* src = (m == 0) ? W_hh : (m == 1) ? (W_ih + G4 * HH) : (W_hh + G4 * HH);
  unsigned* dst = (unsigned*)(ws + ((m == 0) ? OFF_PWHH0 : (m == 1) ? OFF_PWIH1 : OFF_PWHH1));
  const int idx = blockIdx.x * 256 + threadIdx.x;  // [0, 131072)
  const int k2 = idx >> 10, g = idx & 1023;
  const float we = src[(size_t)g * HH + 2 * k2];
  const float wo = src[(size_t)g * HH + 2 * k2 + 1];
  dst[idx] = (unsigned)f2bf(we) | ((unsigned)f2bf(wo) << 16);
}

// ---------------------------------------------------------------------------
// Xg[t*B+b][g] = b_ih0[g] + x[t,b,:] @ W_ih0[g,:]   (fp32, exact)
// ---------------------------------------------------------------------------
__global__ void xg_kernel(const float* __restrict__ x,
                          const float* __restrict__ b_ih,
                          float* __restrict__ ws) {
  const float* __restrict__ WTih0 = ws + OFF_WTIH0;
  float* __restrict__ Xg = ws + OFF_XG;
  const int r0 = blockIdx.x * 16;
  const int g = blockIdx.y * 256 + threadIdx.x;
  __shared__ float xs[16][HH];
  for (int i = threadIdx.x; i < 16 * HH; i += 256)
    xs[i >> 8][i & 255] = x[(size_t)(r0 + (i >> 8)) * HH + (i & 255)];
  __syncthreads();
  float acc[16];
  const float bias = b_ih[g];
#pragma unroll
  for (int r = 0; r < 16; ++r) acc[r] = bias;
  for (int k = 0; k < HH; ++k) {
    const float w = WTih0[(size_t)k * G4 + g];
#pragma unroll
    for (int r = 0; r < 16; ++r) acc[r] = fmaf(xs[r][k], w, acc[r]);
  }
#pragma unroll
  for (int r = 0; r < 16; ++r) Xg[(size_t)(r0 + r) * G4 + g] = acc[r];
}

// ---------------------------------------------------------------------------
// Sequential recurrence. 256 WGs = (half, b); each WG owns 128 h-cols (both
// layers) of batch element b. bf16 packed weights streamed from L2.
// Thread tid: ks = tid>>7 (k-slice 0..7), cq = tid&127 (col quad).
// ---------------------------------------------------------------------------
__global__ void __launch_bounds__(1024)
seq2_kernel(const float* __restrict__ b_ih,
            const float* __restrict__ b_hh,
            const int* __restrict__ ops,
            float* __restrict__ ws,
            float* __restrict__ out) {
  const int b = blockIdx.x & 127;
  const int half = blockIdx.x >> 7;
  const int tid = threadIdx.x;
  const int ks = tid >> 7;     // 0..7
  const int cq = tid & 127;    // col quad
  const int c0 = cq * 4;       // local col base in [0,512)
  const int gbase = (c0 >> 7) * 256 + half * 128 + (c0 & 127);  // global gate col

  const float* __restrict__ Xg = ws + OFF_XG;
  const unsigned* __restrict__ PWHH0 = (const unsigned*)(ws + OFF_PWHH0);
  const unsigned* __restrict__ PWIH1 = (const unsigned*)(ws + OFF_PWIH1);
  const unsigned* __restrict__ PWHH1 = (const unsigned*)(ws + OFF_PWHH1);
  float* __restrict__ hx0 = ws + OFF_HX0;
  float* __restrict__ hx1 = ws + OFF_HX1;
  unsigned* __restrict__ flagsA = (unsigned*)(ws + OFF_FLAGS);
  unsigned* __restrict__ flagsB = flagsA + 256;
  unsigned* myA = flagsA + half * 128 + b;
  unsigned* paA = flagsA + (1 - half) * 128 + b;
  unsigned* myB = flagsB + half * 128 + b;
  unsigned* paB = flagsB + (1 - half) * 128 + b;
  const int pbase = (1 - half) * 128;  // partner h-col base

  __shared__ float hprev0[HH], hprev1[HH], h0full[HH];
  __shared__ float part[4096];
  __shared__ float gat[512];
  __shared__ float bias0_l[512], bias1_l[512];

  // init LDS state + step-invariant biases
  if (tid < HH) { hprev0[tid] = 0.f; hprev1[tid] = 0.f; }
  if (tid < 512) {
    const int gc = (tid >> 7) * 256 + half * 128 + (tid & 127);
    bias0_l[tid] = b_hh[gc];                           // b_ih0 folded into Xg
    bias1_l[tid] = b_ih[G4 + gc] + b_hh[G4 + gc];
  }
  float cp0 = 0.f, cp1 = 0.f;  // cell state, held by threads tid<128
  __syncthreads();

  for (int t = 0; t < TT; ++t) {
    const int op = ops[t * BB + b];

    // ---- phase A: gates0 partial = hprev0 @ W_hh0^T (my cols, my k-slice) ----
    {
      float a0 = 0.f, a1 = 0.f, a2 = 0.f, a3 = 0.f;
      const uint4* wp = ((const uint4*)PWHH0) + (size_t)(ks * 16) * 256 + (gbase >> 2);
#pragma unroll 4
      for (int i = 0; i < 16; ++i) {
        const float2 h2 = *(const float2*)&hprev0[(ks * 16 + i) * 2];
        const uint4 w = wp[(size_t)i * 256];
        a0 = fmaf(blo(w.x), h2.x, fmaf(bhi(w.x), h2.y, a0));
        a1 = fmaf(blo(w.y), h2.x, fmaf(bhi(w.y), h2.y, a1));
        a2 = fmaf(blo(w.z), h2.x, fmaf(bhi(w.z), h2.y, a2));
        a3 = fmaf(blo(w.w), h2.x, fmaf(bhi(w.w), h2.y, a3));
      }
      *(float4*)&part[ks * 512 + c0] = make_float4(a0, a1, a2, a3);
    }
    __syncthreads();
    if (tid < 512) {
      float s = part[tid] + part[512 + tid] + part[1024 + tid] + part[1536 + tid] +
                part[2048 + tid] + part[2560 + tid] + part[3072 + tid] + part[3584 + tid];
      const int gc = (tid >> 7) * 256 + half * 128 + (tid & 127);
      gat[tid] = s + bias0_l[tid] + Xg[((size_t)t * BB + b) * G4 + gc];
    }
    __syncthreads();
    // ---- cell 0 (threads 0..127 own h-cols half*128+tid) ----
    if (tid < 128) {
      const float ig = gat[tid], fg = gat[128 + tid], gg = gat[256 + tid], og = gat[384 + tid];
      const float c = sigf(fg) * cp0 + sigf(ig) * tanhf(gg);
      const float h = sigf(og) * tanhf(c);
      cp0 = op ? c : cp0;
      const int hl = half * 128 + tid;
      h0full[hl] = h;
      hx0[(size_t)b * HH + hl] = h;       // export to partner
      if (op) hprev0[hl] = h;             // phase A of this step already done
    }
    // ---- handshake A ----
    if (tid == 0) {
      __hip_atomic_store(myA, (unsigned)(t + 1), __ATOMIC_RELEASE, __HIP_MEMORY_SCOPE_AGENT);
      while (__hip_atomic_load(paA, __ATOMIC_ACQUIRE, __HIP_MEMORY_SCOPE_AGENT) != (unsigned)(t + 1))
        __builtin_amdgcn_s_sleep(1);
    }
    __syncthreads();
    if (tid < 128) {
      const float v = hx0[(size_t)b * HH + pbase + tid];
      h0full[pbase + tid] = v;
      if (op) hprev0[pbase + tid] = v;
    }
    __syncthreads();

    // ---- phase B: gates1 partial. ks<4: W_ih1 @ h0full; ks>=4: W_hh1 @ hprev1 ----
    {
      const unsigned* PW1 = (ks < 4) ? PWIH1 : PWHH1;
      const float* hsrc = (ks < 4) ? h0full : hprev1;
      const int ksl = ks & 3;
      float a0 = 0.f, a1 = 0.f, a2 = 0.f, a3 = 0.f;
      const uint4* wp = ((const uint4*)PW1) + (size_t)(ksl * 32) * 256 + (gbase >> 2);
#pragma unroll 4
      for (int i = 0; i < 32; ++i) {
        const float2 h2 = *(const float2*)&hsrc[(ksl * 32 + i) * 2];
        const uint4 w = wp[(size_t)i * 256];
        a0 = fmaf(blo(w.x), h2.x, fmaf(bhi(w.x), h2.y, a0));
        a1 = fmaf(blo(w.y), h2.x, fmaf(bhi(w.y), h2.y, a1));
        a2 = fmaf(blo(w.z), h2.x, fmaf(bhi(w.z), h2.y, a2));
        a3 = fmaf(blo(w.w), h2.x, fmaf(bhi(w.w), h2.y, a3));
      }
      *(float4*)&part[ks * 512 + c0] = make_float4(a0, a1, a2, a3);
    }
    __syncthreads();
    if (tid < 512) {
      float s = part[tid] + part[512 + tid] + part[1024 + tid] + part[1536 + tid] +
                part[2048 + tid] + part[2560 + tid] + part[3072 + tid] + part[3584 + tid];
      gat[tid] = s + bias1_l[tid];
    }
    __syncthreads();
    // ---- cell 1 + output ----
    if (tid < 128) {
      const float ig = gat[tid], fg = gat[128 + tid], gg = gat[256 + tid], og = gat[384 + tid];
      const float c = sigf(fg) * cp1 + sigf(ig) * tanhf(gg);
      const float h = sigf(og) * tanhf(c);
      cp1 = op ? c : cp1;
      const int hl = half * 128 + tid;
      out[((size_t)t * BB + b) * HH + hl] = h;
      hx1[(size_t)b * HH + hl] = h;
      if (op) hprev1[hl] = h;             // phase B reads of hprev1 done
    }
    // ---- handshake B ----
    if (tid == 0) {
      __hip_atomic_store(myB, (unsigned)(t + 1), __ATOMIC_RELEASE, __HIP_MEMORY_SCOPE_AGENT);
      while (__hip_atomic_load(paB, __ATOMIC_ACQUIRE, __HIP_MEMORY_SCOPE_AGENT) != (unsigned)(t + 1))
        __builtin_amdgcn_s_sleep(1);
    }
    __syncthreads();
    if (tid < 128 && op) hprev1[pbase + tid] = hx1[(size_t)b * HH + pbase + tid];
    __syncthreads();
  }
}

// ---------------------------------------------------------------------------
extern "C" void kernel_launch(void* const* d_in, const int* in_sizes, int n_in,
                              void* d_out, int out_size, void* d_ws, size_t ws_size,
                              hipStream_t stream) {
  const float* x    = (const float*)d_in[0];
  const int*   ops  = (const int*)d_in[1];
  const float* W_ih = (const float*)d_in[2];
  const float* W_hh = (const float*)d_in[3];
  const float* b_ih = (const float*)d_in[4];
  const float* b_hh = (const float*)d_in[5];
  float* out = (float*)d_out;
  float* ws  = (float*)d_ws;

  transpose1<<<dim3(32, 8), dim3(32, 8), 0, stream>>>(W_ih, ws);
  pack_bf16<<<dim3(512, 3), 256, 0, stream>>>(W_ih, W_hh, ws);
  xg_kernel<<<dim3(512, 4), 256, 0, stream>>>(x, b_ih, ws);
  seq2_kernel<<<256, 1024, 0, stream>>>(b_ih, b_hh, ops, ws, out);
}